// Round 2
// baseline (1932.689 us; speedup 1.0000x reference)
//
#include <hip/hip_runtime.h>
#include <stdint.h>

// Persistent-kernel LSTM NAS controller rollout.
// RNG: JAX threefry2x32 with jax_threefry_partitionable=True (default since
// JAX 0.4.36): split row i = tf(key,(0,i)) pair; random_bits[i] = fold
// x0^x1 of tf(key,(0,i)).
// 128 wgs x 256 thr; each wave owns 1 of 512 hidden units, weights register-stationary.
// 3 device-scope barriers/step + 2 sampler-broadcast flags (wg0 = sampler).

#define KWG    128
#define NTH    256
#define LSTEPS 32
#define DDIM   512
#define NOPS   16
#define NEGC   (-1.0e9f)
#define MAGICV 0x13579BDFu

// ---------------- threefry2x32 core ----------------
static __device__ __forceinline__ void tf2x32(uint32_t k0, uint32_t k1,
                                              uint32_t c0, uint32_t c1,
                                              uint32_t& o0, uint32_t& o1){
  uint32_t ks2 = k0 ^ k1 ^ 0x1BD11BDAu;
  uint32_t x0 = c0 + k0;
  uint32_t x1 = c1 + k1;
#define TFR(r) { x0 += x1; x1 = (x1 << (r)) | (x1 >> (32 - (r))); x1 ^= x0; }
  TFR(13) TFR(15) TFR(26) TFR(6)
  x0 += k1;  x1 += ks2 + 1u;
  TFR(17) TFR(29) TFR(16) TFR(24)
  x0 += ks2; x1 += k0 + 2u;
  TFR(13) TFR(15) TFR(26) TFR(6)
  x0 += k0;  x1 += k1 + 3u;
  TFR(17) TFR(29) TFR(16) TFR(24)
  x0 += k1;  x1 += ks2 + 4u;
  TFR(13) TFR(15) TFR(26) TFR(6)
  x0 += ks2; x1 += k0 + 5u;
#undef TFR
  o0 = x0; o1 = x1;
}

// JAX uniform(tiny,1) -> gumbel:  u = bits>>9 | 1.0f mantissa trick
static __device__ __forceinline__ float gumbel_bits(uint32_t bits){
  float f = __uint_as_float((bits >> 9) | 0x3f800000u) - 1.0f;
  float u = (f == 0.0f) ? 1.1754943508222875e-38f : f;
  return -logf(-logf(u));
}

static __device__ __forceinline__ float sigm(float x){
  return 1.0f / (1.0f + expf(-x));
}

static __device__ __forceinline__ float wredsum(float v){
  #pragma unroll
  for (int m = 32; m; m >>= 1) v += __shfl_xor(v, m, 64);
  return v;   // all lanes hold the sum
}

static __device__ __forceinline__ void load8(const float* __restrict__ p, float* r){
  const float4* q = (const float4*)p;
  float4 a = q[0], b = q[1];
  r[0]=a.x; r[1]=a.y; r[2]=a.z; r[3]=a.w;
  r[4]=b.x; r[5]=b.y; r[6]=b.z; r[7]=b.w;
}

static __device__ __forceinline__ float dot8(const float* w, const float* x){
  float s = 0.f;
  #pragma unroll
  for (int k = 0; k < 8; ++k) s += w[k]*x[k];
  return s;
}

static __device__ __forceinline__ uint32_t aldu(const uint32_t* p){
  return __hip_atomic_load(p, __ATOMIC_RELAXED, __HIP_MEMORY_SCOPE_AGENT);
}
static __device__ __forceinline__ void astf(float* p, float v){
  __hip_atomic_store(p, v, __ATOMIC_RELAXED, __HIP_MEMORY_SCOPE_AGENT);
}

static __device__ __forceinline__ void wg_arrive(uint32_t* slot, uint32_t ph){
  __threadfence();          // make this thread's global stores agent-visible
  __syncthreads();          // whole wg fenced before the flag
  if (threadIdx.x == 0)
    __hip_atomic_store(slot, ph, __ATOMIC_RELEASE, __HIP_MEMORY_SCOPE_AGENT);
}

static __device__ __forceinline__ void wg_poll_all(const uint32_t* flags, uint32_t ph){
  if (threadIdx.x < KWG){
    while (aldu(flags + (threadIdx.x << 4)) < ph) { }
  }
  __threadfence();          // acquire: invalidate caches before data reads
  __syncthreads();
}

__global__ void __launch_bounds__(NTH, 1)
Controller_60601988547087_kernel(const float* __restrict__ emb,
                                 const float* __restrict__ wih,
                                 const float* __restrict__ whh,
                                 const float* __restrict__ bih,
                                 const float* __restrict__ bhh,
                                 const float* __restrict__ wa1,
                                 const float* __restrict__ wa2,
                                 const float* __restrict__ idxfc,
                                 const float* __restrict__ opfc,
                                 float* __restrict__ out,
                                 uint32_t* __restrict__ wsu)
{
  const int tid  = threadIdx.x;
  const int wg   = blockIdx.x;
  const int wave = tid >> 6;
  const int lane = tid & 63;
  const int unit = (wg << 2) | wave;     // one hidden unit per wave, 512 total

  // workspace layout (u32 units)
  uint32_t* flags  = wsu;                // [128] stride 16 (64B)
  uint32_t* magicf = wsu + 2048;         // [128] stride 16
  uint32_t* nflag  = wsu + 4096;         // [32]
  uint32_t* oflag  = wsu + 4128;         // [32]
  float*    wsf    = (float*)(wsu + 8192);
  float*    bufA   = wsf;                // h after cell1   [512]
  float*    bufB   = wsf + 512;          // h after cell2 / carry h  [512]
  float*    hw2g   = wsf + 1024;         // h1 @ w_attn_2^T [512]
  float*    aw1g   = wsf + 2048;         // anchors_w1 [33][512]
  float*    anch   = wsf + 18944;        // anchors    [33][512]

  __shared__ float s_opfc[NOPS * DDIM];  // 32 KB, used by wg0 only
  __shared__ float s_logits[33];
  __shared__ float s_oplog[16];
  __shared__ int   s_ibc[2];

  // ---- stage weights into registers (row-partitioned; read from HBM once) ----
  float wihr[4][8], whhr[4][8], a1r[8], a2r[8], fcr[8], bsum[4];
  #pragma unroll
  for (int g = 0; g < 4; ++g){
    load8(wih + (size_t)((g << 9) + unit) * DDIM + (lane << 3), wihr[g]);
    load8(whh + (size_t)((g << 9) + unit) * DDIM + (lane << 3), whhr[g]);
    bsum[g] = bih[(g << 9) + unit] + bhh[(g << 9) + unit];
  }
  load8(wa1 + (size_t)unit * DDIM + (lane << 3), a1r);
  load8(wa2 + (size_t)unit * DDIM + (lane << 3), a2r);
  load8(idxfc + (lane << 3), fcr);

  if (wg == 0){
    for (int i = tid; i < NOPS * DDIM; i += NTH) s_opfc[i] = opfc[i];
  }

  // ---- initial construct_node: h,c = cell(emb[16], 0, 0) ----
  float cst;
  {
    float xc[8];
    load8(emb + (size_t)NOPS * DDIM + (lane << 3), xc);
    float p0 = dot8(wihr[0], xc);
    float p1 = dot8(wihr[1], xc);
    float p2 = dot8(wihr[2], xc);
    float p3 = dot8(wihr[3], xc);
    p0 = wredsum(p0); p1 = wredsum(p1); p2 = wredsum(p2); p3 = wredsum(p3);
    (void)p1; // sigmoid(f)*c with c=0 contributes 0 exactly
    float gi = sigm(p0 + bsum[0]);
    float go = sigm(p3 + bsum[3]);
    cst = gi * tanhf(p2 + bsum[2]);
    float h0 = go * tanhf(cst);
    if (lane == 0){
      astf(bufB + unit, h0);     // carry h
      astf(anch + unit, 0.0f);   // anchors[0] = zeros
    }
  }
  if (tid == 0)
    __hip_atomic_store(flags + (wg << 4), 0u, __ATOMIC_RELAXED, __HIP_MEMORY_SCOPE_AGENT);
  // init barrier: exact-match magic (poison-safe: 0xAAAAAAAA != MAGICV)
  __threadfence();
  __syncthreads();
  if (tid == 0)
    __hip_atomic_store(magicf + (wg << 4), MAGICV, __ATOMIC_RELEASE, __HIP_MEMORY_SCOPE_AGENT);
  if (tid < KWG){ while (aldu(magicf + (tid << 4)) != MAGICV) { } }
  __threadfence();
  __syncthreads();

  uint32_t key0 = 0u, key1v = 42u;       // jax.random.key(42) -> (0, 42)
  float ent_sum = 0.f, lp_sum = 0.f;
  int prev_op = NOPS;                    // inp0 = embedding[16]
  uint32_t ph = 0;

  for (int t = 0; t < LSTEPS; ++t){
    // ================= Stage A: cell1 + anchors_w1[t] =================
    {
      float xc[8], hc[8];
      load8(emb + (size_t)prev_op * DDIM + (lane << 3), xc);
      load8(bufB + (lane << 3), hc);
      float p0 = dot8(wihr[0], xc) + dot8(whhr[0], hc);
      float p1 = dot8(wihr[1], xc) + dot8(whhr[1], hc);
      float p2 = dot8(wihr[2], xc) + dot8(whhr[2], hc);
      float p3 = dot8(wihr[3], xc) + dot8(whhr[3], hc);
      float pa = dot8(a1r, hc);          // aw1[t][unit] from carry h
      p0 = wredsum(p0); p1 = wredsum(p1); p2 = wredsum(p2); p3 = wredsum(p3);
      pa = wredsum(pa);
      float gi = sigm(p0 + bsum[0]);
      float gf = sigm(p1 + bsum[1]);
      float go = sigm(p3 + bsum[3]);
      cst = gf * cst + gi * tanhf(p2 + bsum[2]);
      float hn = go * tanhf(cst);
      if (lane == 0){
        astf(bufA + unit, hn);
        astf(aw1g + (size_t)t * DDIM + unit, pa);
      }
    }
    ++ph; wg_arrive(flags + (wg << 4), ph);
    wg_poll_all(flags, ph);              // B1: everyone needs full h1

    // ============ Stage B: hw2 slice + cell2 h-part precompute ============
    float ghh0, ghh1, ghh2, ghh3;
    {
      float h1c[8];
      load8(bufA + (lane << 3), h1c);
      float q  = dot8(a2r, h1c);
      float g0 = dot8(whhr[0], h1c);
      float g1 = dot8(whhr[1], h1c);
      float g2 = dot8(whhr[2], h1c);
      float g3 = dot8(whhr[3], h1c);
      q = wredsum(q);
      ghh0 = wredsum(g0); ghh1 = wredsum(g1); ghh2 = wredsum(g2); ghh3 = wredsum(g3);
      if (lane == 0) astf(hw2g + unit, q);
    }
    ++ph; wg_arrive(flags + (wg << 4), ph);   // B2: gather to wg0

    int ni;
    float nlp_s = 0.f, nent_s = 0.f;
    uint32_t k2a_s = 0u, k2b_s = 0u;
    if (wg == 0){
      wg_poll_all(flags, ph);
      // node logits, rows 0..t split over 4 waves
      {
        float h2c[8]; load8(hw2g + (lane << 3), h2c);
        for (int i = wave; i <= t; i += 4){
          float ac[8]; load8(aw1g + (size_t)i * DDIM + (lane << 3), ac);
          float acc = 0.f;
          #pragma unroll
          for (int k = 0; k < 8; ++k) acc += tanhf(ac[k] + h2c[k]) * fcr[k];
          acc = wredsum(acc);
          if (lane == 0) s_logits[i] = 2.5f * tanhf(acc / 5.0f);
        }
      }
      __syncthreads();
      if (wave == 0){
        // split(key,3), partitionable/foldlike: row i = tf(key, (0, i))
        uint32_t s0 = 0, s1 = 0;
        if (lane < 3) tf2x32(key0, key1v, 0u, (uint32_t)lane, s0, s1);
        uint32_t k1a = __shfl(s0, 0, 64), k1b = __shfl(s1, 0, 64);
        k2a_s = __shfl(s0, 1, 64); k2b_s = __shfl(s1, 1, 64);
        uint32_t nk0 = __shfl(s0, 2, 64), nk1 = __shfl(s1, 2, 64);
        key0 = nk0; key1v = nk1;
        // 33 random bits, partitionable: bits[i] = x0 ^ x1 of tf(k1, (0, i))
        uint32_t y0 = 0, y1 = 0;
        if (lane < 33) tf2x32(k1a, k1b, 0u, (uint32_t)lane, y0, y1);
        uint32_t bits = y0 ^ y1;
        float gmb   = gumbel_bits(bits);
        float logit = (lane < 33) ? ((lane <= t) ? s_logits[lane] : NEGC) : -3.0e38f;
        float cand  = (lane < 33) ? (logit + gmb) : -3.0e38f;
        float v = cand; int bi = lane;
        #pragma unroll
        for (int m = 32; m; m >>= 1){
          float ov = __shfl_xor(v, m, 64); int ob = __shfl_xor(bi, m, 64);
          if (ov > v || (ov == v && ob < bi)){ v = ov; bi = ob; }
        }
        int ni_ = bi;
        float lm = (lane < 33) ? logit : -3.0e38f;
        #pragma unroll
        for (int m = 32; m; m >>= 1) lm = fmaxf(lm, __shfl_xor(lm, m, 64));
        float ex   = (lane < 33) ? expf(logit - lm) : 0.f;
        float ssum = wredsum(ex);
        float lsm  = logit - lm - logf(ssum);
        nlp_s  = -__shfl(lsm, ni_, 64);
        float entc = (lane <= t) ? (-lsm * expf(lsm)) : 0.f;
        nent_s = wredsum(entc);
        if (lane == 0){
          s_ibc[0] = ni_;
          __hip_atomic_store(nflag + t, 0x5A5A0000u | (uint32_t)ni_,
                             __ATOMIC_RELEASE, __HIP_MEMORY_SCOPE_AGENT);
        }
      }
      __syncthreads();
      ni = s_ibc[0];
    } else {
      if (tid == 0){
        uint32_t v;
        do { v = aldu(nflag + t); } while ((v >> 16) != 0x5A5Au);
        s_ibc[0] = (int)(v & 0xFFFFu);
      }
      __threadfence();
      __syncthreads();
      ni = s_ibc[0];
    }

    // ================= Stage C: cell2 (op_in = anchors[ni]) =================
    {
      float oc8[8];
      load8(anch + (size_t)ni * DDIM + (lane << 3), oc8);
      float q0 = dot8(wihr[0], oc8);
      float q1 = dot8(wihr[1], oc8);
      float q2 = dot8(wihr[2], oc8);
      float q3 = dot8(wihr[3], oc8);
      q0 = wredsum(q0); q1 = wredsum(q1); q2 = wredsum(q2); q3 = wredsum(q3);
      float gi = sigm(q0 + ghh0 + bsum[0]);
      float gf = sigm(q1 + ghh1 + bsum[1]);
      float go = sigm(q3 + ghh3 + bsum[3]);
      cst = gf * cst + gi * tanhf(q2 + ghh2 + bsum[2]);
      float hn = go * tanhf(cst);
      if (lane == 0){
        astf(bufB + unit, hn);
        astf(anch + (size_t)(t + 1) * DDIM + unit, hn);
      }
    }
    ++ph; wg_arrive(flags + (wg << 4), ph);   // B3: gather to wg0

    int oi;
    if (wg == 0){
      wg_poll_all(flags, ph);
      {
        float hc2[8]; load8(bufB + (lane << 3), hc2);
        for (int i = wave; i < 16; i += 4){
          float acc = 0.f;
          #pragma unroll
          for (int k = 0; k < 8; ++k) acc += s_opfc[i * DDIM + (lane << 3) + k] * hc2[k];
          acc = wredsum(acc);
          if (lane == 0) s_oplog[i] = tanhf(acc / 5.0f);  // (2.5/2.5)=1.0 scale
        }
      }
      __syncthreads();
      if (wave == 0){
        // 16 random bits, partitionable: bits[i] = x0 ^ x1 of tf(k2, (0, i))
        uint32_t z0 = 0, z1 = 0;
        if (lane < 16) tf2x32(k2a_s, k2b_s, 0u, (uint32_t)lane, z0, z1);
        uint32_t bits = z0 ^ z1;
        float gmb   = gumbel_bits(bits);
        float logit = (lane < 16) ? s_oplog[lane] : -3.0e38f;
        float cand  = (lane < 16) ? (logit + gmb) : -3.0e38f;
        float v = cand; int bi = lane;
        #pragma unroll
        for (int m = 32; m; m >>= 1){
          float ov = __shfl_xor(v, m, 64); int ob = __shfl_xor(bi, m, 64);
          if (ov > v || (ov == v && ob < bi)){ v = ov; bi = ob; }
        }
        int oi_ = bi;
        float lm = (lane < 16) ? logit : -3.0e38f;
        #pragma unroll
        for (int m = 32; m; m >>= 1) lm = fmaxf(lm, __shfl_xor(lm, m, 64));
        float ex   = (lane < 16) ? expf(logit - lm) : 0.f;
        float ssum = wredsum(ex);
        float olsm = logit - lm - logf(ssum);
        float olp  = -__shfl(olsm, oi_, 64);
        float oent = wredsum((lane < 16) ? (-olsm * expf(olsm)) : 0.f);
        lp_sum  += nlp_s + olp;
        ent_sum += nent_s + oent;
        if (lane == 0){
          s_ibc[1] = oi_;
          out[2 * t]     = (float)ni;
          out[2 * t + 1] = (float)oi_;
          __hip_atomic_store(oflag + t, 0x5A5A0000u | (uint32_t)oi_,
                             __ATOMIC_RELEASE, __HIP_MEMORY_SCOPE_AGENT);
        }
      }
      __syncthreads();
      oi = s_ibc[1];
    } else {
      if (tid == 0){
        uint32_t v;
        do { v = aldu(oflag + t); } while ((v >> 16) != 0x5A5Au);
        s_ibc[1] = (int)(v & 0xFFFFu);
      }
      __threadfence();
      __syncthreads();
      oi = s_ibc[1];
    }
    prev_op = oi;
  }

  if (wg == 0 && wave == 0 && lane == 0){
    out[64] = ent_sum;
    out[65] = lp_sum;
  }
}

extern "C" void kernel_launch(void* const* d_in, const int* in_sizes, int n_in,
                              void* d_out, int out_size, void* d_ws, size_t ws_size,
                              hipStream_t stream) {
  (void)in_sizes; (void)n_in; (void)out_size; (void)ws_size;
  const float* emb  = (const float*)d_in[0];
  const float* wih  = (const float*)d_in[1];
  const float* whh  = (const float*)d_in[2];
  const float* bih  = (const float*)d_in[3];
  const float* bhh  = (const float*)d_in[4];
  const float* wa1  = (const float*)d_in[5];
  const float* wa2  = (const float*)d_in[6];
  const float* ifc  = (const float*)d_in[7];
  const float* ofc  = (const float*)d_in[8];
  float* out = (float*)d_out;
  uint32_t* ws = (uint32_t*)d_ws;
  hipLaunchKernelGGL(Controller_60601988547087_kernel,
                     dim3(KWG), dim3(NTH), 0, stream,
                     emb, wih, whh, bih, bhh, wa1, wa2, ifc, ofc, out, ws);
}

// Round 3
// 1655.190 us; speedup vs baseline: 1.1677x; 1.1677x over previous
//
#include <hip/hip_runtime.h>
#include <stdint.h>

// Persistent-kernel LSTM NAS controller rollout.
// RNG: JAX threefry2x32, jax_threefry_partitionable=True (default >=0.4.36):
//   split row i = tf(key,(0,i)); random_bits[i] = fold x0^x1 of tf(key,(0,i)).
// 32 wgs x 1024 thr (16 waves/WG, 512 waves total; one hidden unit per wave,
// weights register-stationary). Sync fabric: single monotone arrival counter
// (atomicAdd agent) + one polling thread per WG with s_sleep backoff;
// index broadcast via exact-match release flags. wg0 = sampler.

#define KWG    32
#define NTH    1024
#define LSTEPS 32
#define DDIM   512
#define NOPS   16
#define NEGC   (-1.0e9f)
#define MAGICV 0x13579BDFu

// ---------------- threefry2x32 core ----------------
static __device__ __forceinline__ void tf2x32(uint32_t k0, uint32_t k1,
                                              uint32_t c0, uint32_t c1,
                                              uint32_t& o0, uint32_t& o1){
  uint32_t ks2 = k0 ^ k1 ^ 0x1BD11BDAu;
  uint32_t x0 = c0 + k0;
  uint32_t x1 = c1 + k1;
#define TFR(r) { x0 += x1; x1 = (x1 << (r)) | (x1 >> (32 - (r))); x1 ^= x0; }
  TFR(13) TFR(15) TFR(26) TFR(6)
  x0 += k1;  x1 += ks2 + 1u;
  TFR(17) TFR(29) TFR(16) TFR(24)
  x0 += ks2; x1 += k0 + 2u;
  TFR(13) TFR(15) TFR(26) TFR(6)
  x0 += k0;  x1 += k1 + 3u;
  TFR(17) TFR(29) TFR(16) TFR(24)
  x0 += k1;  x1 += ks2 + 4u;
  TFR(13) TFR(15) TFR(26) TFR(6)
  x0 += ks2; x1 += k0 + 5u;
#undef TFR
  o0 = x0; o1 = x1;
}

static __device__ __forceinline__ float gumbel_bits(uint32_t bits){
  float f = __uint_as_float((bits >> 9) | 0x3f800000u) - 1.0f;
  float u = (f == 0.0f) ? 1.1754943508222875e-38f : f;
  return -logf(-logf(u));
}

static __device__ __forceinline__ float sigm(float x){
  return 1.0f / (1.0f + expf(-x));
}

static __device__ __forceinline__ float wredsum(float v){
  #pragma unroll
  for (int m = 32; m; m >>= 1) v += __shfl_xor(v, m, 64);
  return v;
}

static __device__ __forceinline__ void load8(const float* __restrict__ p, float* r){
  const float4* q = (const float4*)p;
  float4 a = q[0], b = q[1];
  r[0]=a.x; r[1]=a.y; r[2]=a.z; r[3]=a.w;
  r[4]=b.x; r[5]=b.y; r[6]=b.z; r[7]=b.w;
}

static __device__ __forceinline__ float dot8(const float* w, const float* x){
  float s = 0.f;
  #pragma unroll
  for (int k = 0; k < 8; ++k) s += w[k]*x[k];
  return s;
}

static __device__ __forceinline__ uint32_t aldu(const uint32_t* p){
  return __hip_atomic_load(p, __ATOMIC_RELAXED, __HIP_MEMORY_SCOPE_AGENT);
}
static __device__ __forceinline__ void astf(float* p, float v){
  __hip_atomic_store(p, v, __ATOMIC_RELAXED, __HIP_MEMORY_SCOPE_AGENT);
}

// arrive: every thread fences its (sc1/agent) data stores to the coherence
// point, wg-barrier, then one thread bumps the global arrival counter.
static __device__ __forceinline__ void bar_arrive(uint32_t* ctr){
  __builtin_amdgcn_fence(__ATOMIC_RELEASE, "agent");
  __syncthreads();
  if (threadIdx.x == 0)
    __hip_atomic_fetch_add(ctr, 1u, __ATOMIC_RELAXED, __HIP_MEMORY_SCOPE_AGENT);
}

// wait: ONE thread polls the counter (with s_sleep backoff to keep the
// fabric quiet), then all threads acquire-fence before reading shared data.
static __device__ __forceinline__ void bar_wait(const uint32_t* ctr, uint32_t tgt){
  if (threadIdx.x == 0){
    while (aldu(ctr) < tgt) __builtin_amdgcn_s_sleep(1);
  }
  __syncthreads();
  __builtin_amdgcn_fence(__ATOMIC_ACQUIRE, "agent");
}

__global__ void __launch_bounds__(NTH, 1)
Controller_60601988547087_kernel(const float* __restrict__ emb,
                                 const float* __restrict__ wih,
                                 const float* __restrict__ whh,
                                 const float* __restrict__ bih,
                                 const float* __restrict__ bhh,
                                 const float* __restrict__ wa1,
                                 const float* __restrict__ wa2,
                                 const float* __restrict__ idxfc,
                                 const float* __restrict__ opfc,
                                 float* __restrict__ out,
                                 uint32_t* __restrict__ wsu)
{
  const int tid  = threadIdx.x;
  const int wg   = blockIdx.x;
  const int wave = tid >> 6;              // 0..15
  const int lane = tid & 63;
  const int unit = (wg << 4) | wave;      // one hidden unit per wave, 512 total

  // workspace layout (u32 units)
  uint32_t* magicf = wsu;                 // [32] stride 16 (64B lines)
  uint32_t* barctr = wsu + 1024;          // single monotone arrival counter
  uint32_t* nflag  = wsu + 1536;          // [32] node-index broadcast
  uint32_t* oflag  = wsu + 1664;          // [32] op-index broadcast
  float*    wsf    = (float*)(wsu + 4096);
  float*    bufA   = wsf;                 // h after cell1   [512]
  float*    bufB   = wsf + 512;           // h after cell2 / carry h [512]
  float*    hw2g   = wsf + 1024;          // h1 @ w_attn_2^T [512]
  float*    aw1g   = wsf + 1536;          // anchors_w1 [33][512]
  float*    anch   = wsf + 18432;         // anchors    [33][512]

  __shared__ float s_opfc[NOPS * DDIM];   // 32 KB, used by wg0 only
  __shared__ float s_logits[33];
  __shared__ float s_oplog[16];
  __shared__ int   s_ibc[2];

  // ---- stage weights into registers (read from HBM once) ----
  float wihr[4][8], whhr[4][8], a1r[8], a2r[8], fcr[8], bsum[4];
  #pragma unroll
  for (int g = 0; g < 4; ++g){
    load8(wih + (size_t)((g << 9) + unit) * DDIM + (lane << 3), wihr[g]);
    load8(whh + (size_t)((g << 9) + unit) * DDIM + (lane << 3), whhr[g]);
    bsum[g] = bih[(g << 9) + unit] + bhh[(g << 9) + unit];
  }
  load8(wa1 + (size_t)unit * DDIM + (lane << 3), a1r);
  load8(wa2 + (size_t)unit * DDIM + (lane << 3), a2r);
  load8(idxfc + (lane << 3), fcr);

  if (wg == 0){
    for (int i = tid; i < NOPS * DDIM; i += NTH) s_opfc[i] = opfc[i];
  }

  // ---- initial construct_node: h,c = cell(emb[16], 0, 0) ----
  float cst;
  {
    float xc[8];
    load8(emb + (size_t)NOPS * DDIM + (lane << 3), xc);
    float p0 = dot8(wihr[0], xc);
    float p2 = dot8(wihr[2], xc);
    float p3 = dot8(wihr[3], xc);
    p0 = wredsum(p0); p2 = wredsum(p2); p3 = wredsum(p3);
    float gi = sigm(p0 + bsum[0]);
    float go = sigm(p3 + bsum[3]);
    cst = gi * tanhf(p2 + bsum[2]);      // c=0: forget-gate term vanishes exactly
    float h0 = go * tanhf(cst);
    if (lane == 0){
      astf(bufB + unit, h0);             // carry h
      astf(anch + unit, 0.0f);           // anchors[0] = zeros
    }
  }
  // zero the arrival counter before anyone can touch it (0xAA poison!)
  if (wg == 0 && tid == 0)
    __hip_atomic_store(barctr, 0u, __ATOMIC_RELAXED, __HIP_MEMORY_SCOPE_AGENT);
  // init barrier: exact-match magic (poison-safe: 0xAAAAAAAA != MAGICV)
  __builtin_amdgcn_fence(__ATOMIC_RELEASE, "agent");
  __syncthreads();
  if (tid == 0)
    __hip_atomic_store(magicf + (wg << 4), MAGICV, __ATOMIC_RELEASE, __HIP_MEMORY_SCOPE_AGENT);
  if (tid < KWG){
    while (aldu(magicf + (tid << 4)) != MAGICV) __builtin_amdgcn_s_sleep(1);
  }
  __syncthreads();
  __builtin_amdgcn_fence(__ATOMIC_ACQUIRE, "agent");

  uint32_t key0 = 0u, key1v = 42u;       // jax.random.key(42) -> (0, 42)
  float ent_sum = 0.f, lp_sum = 0.f;
  int prev_op = NOPS;                    // inp0 = embedding[16]
  uint32_t tgt = 0;                      // barrier target (monotone counter)

  for (int t = 0; t < LSTEPS; ++t){
    // ================= Stage A: cell1 + anchors_w1[t] =================
    {
      float xc[8], hc[8];
      load8(emb + (size_t)prev_op * DDIM + (lane << 3), xc);
      load8(bufB + (lane << 3), hc);
      float p0 = dot8(wihr[0], xc) + dot8(whhr[0], hc);
      float p1 = dot8(wihr[1], xc) + dot8(whhr[1], hc);
      float p2 = dot8(wihr[2], xc) + dot8(whhr[2], hc);
      float p3 = dot8(wihr[3], xc) + dot8(whhr[3], hc);
      float pa = dot8(a1r, hc);          // aw1[t][unit] from carry h
      p0 = wredsum(p0); p1 = wredsum(p1); p2 = wredsum(p2); p3 = wredsum(p3);
      pa = wredsum(pa);
      float gi = sigm(p0 + bsum[0]);
      float gf = sigm(p1 + bsum[1]);
      float go = sigm(p3 + bsum[3]);
      cst = gf * cst + gi * tanhf(p2 + bsum[2]);
      float hn = go * tanhf(cst);
      if (lane == 0){
        astf(bufA + unit, hn);
        astf(aw1g + (size_t)t * DDIM + unit, pa);
      }
    }
    bar_arrive(barctr); tgt += KWG;      // B1
    bar_wait(barctr, tgt);               // everyone needs full h1

    // ============ Stage B: hw2 slice, then cell2 h-part precompute ============
    {
      float h1c[8];
      load8(bufA + (lane << 3), h1c);
      float q = dot8(a2r, h1c);
      q = wredsum(q);
      if (lane == 0) astf(hw2g + unit, q);
    }
    bar_arrive(barctr); tgt += KWG;      // B2 (only wg0 will wait on it)

    float ghh0, ghh1, ghh2, ghh3;        // overlapped with wg0's gather+sample
    {
      float h1c[8];
      load8(bufA + (lane << 3), h1c);
      ghh0 = wredsum(dot8(whhr[0], h1c));
      ghh1 = wredsum(dot8(whhr[1], h1c));
      ghh2 = wredsum(dot8(whhr[2], h1c));
      ghh3 = wredsum(dot8(whhr[3], h1c));
    }

    int ni;
    float nlp_s = 0.f, nent_s = 0.f;
    uint32_t k2a_s = 0u, k2b_s = 0u;
    if (wg == 0){
      bar_wait(barctr, tgt);             // full hw2 + aw1g rows visible
      {
        float h2c[8]; load8(hw2g + (lane << 3), h2c);
        for (int i = wave; i <= t; i += 16){
          float ac[8]; load8(aw1g + (size_t)i * DDIM + (lane << 3), ac);
          float acc = 0.f;
          #pragma unroll
          for (int k = 0; k < 8; ++k) acc += tanhf(ac[k] + h2c[k]) * fcr[k];
          acc = wredsum(acc);
          if (lane == 0) s_logits[i] = 2.5f * tanhf(acc / 5.0f);
        }
      }
      __syncthreads();
      if (wave == 0){
        // split(key,3), partitionable/foldlike: row i = tf(key, (0, i))
        uint32_t s0 = 0, s1 = 0;
        if (lane < 3) tf2x32(key0, key1v, 0u, (uint32_t)lane, s0, s1);
        uint32_t k1a = __shfl(s0, 0, 64), k1b = __shfl(s1, 0, 64);
        k2a_s = __shfl(s0, 1, 64); k2b_s = __shfl(s1, 1, 64);
        uint32_t nk0 = __shfl(s0, 2, 64), nk1 = __shfl(s1, 2, 64);
        key0 = nk0; key1v = nk1;
        // 33 random bits: bits[i] = x0 ^ x1 of tf(k1, (0, i))
        uint32_t y0 = 0, y1 = 0;
        if (lane < 33) tf2x32(k1a, k1b, 0u, (uint32_t)lane, y0, y1);
        uint32_t bits = y0 ^ y1;
        float gmb   = gumbel_bits(bits);
        float logit = (lane < 33) ? ((lane <= t) ? s_logits[lane] : NEGC) : -3.0e38f;
        float cand  = (lane < 33) ? (logit + gmb) : -3.0e38f;
        float v = cand; int bi = lane;
        #pragma unroll
        for (int m = 32; m; m >>= 1){
          float ov = __shfl_xor(v, m, 64); int ob = __shfl_xor(bi, m, 64);
          if (ov > v || (ov == v && ob < bi)){ v = ov; bi = ob; }
        }
        int ni_ = bi;
        float lm = (lane < 33) ? logit : -3.0e38f;
        #pragma unroll
        for (int m = 32; m; m >>= 1) lm = fmaxf(lm, __shfl_xor(lm, m, 64));
        float ex   = (lane < 33) ? expf(logit - lm) : 0.f;
        float ssum = wredsum(ex);
        float lsm  = logit - lm - logf(ssum);
        nlp_s  = -__shfl(lsm, ni_, 64);
        float entc = (lane <= t) ? (-lsm * expf(lsm)) : 0.f;
        nent_s = wredsum(entc);
        if (lane == 0){
          s_ibc[0] = ni_;
          __hip_atomic_store(nflag + t, 0x5A5A0000u | (uint32_t)ni_,
                             __ATOMIC_RELEASE, __HIP_MEMORY_SCOPE_AGENT);
        }
      }
      __syncthreads();
      ni = s_ibc[0];
    } else {
      if (tid == 0){
        uint32_t v;
        while (((v = aldu(nflag + t)) >> 16) != 0x5A5Au) __builtin_amdgcn_s_sleep(1);
        s_ibc[0] = (int)(v & 0xFFFFu);
      }
      __syncthreads();
      __builtin_amdgcn_fence(__ATOMIC_ACQUIRE, "agent");
      ni = s_ibc[0];
    }

    // ================= Stage C: cell2 (op_in = anchors[ni]) =================
    {
      float oc8[8];
      load8(anch + (size_t)ni * DDIM + (lane << 3), oc8);
      float q0 = dot8(wihr[0], oc8);
      float q1 = dot8(wihr[1], oc8);
      float q2 = dot8(wihr[2], oc8);
      float q3 = dot8(wihr[3], oc8);
      q0 = wredsum(q0); q1 = wredsum(q1); q2 = wredsum(q2); q3 = wredsum(q3);
      float gi = sigm(q0 + ghh0 + bsum[0]);
      float gf = sigm(q1 + ghh1 + bsum[1]);
      float go = sigm(q3 + ghh3 + bsum[3]);
      cst = gf * cst + gi * tanhf(q2 + ghh2 + bsum[2]);
      float hn = go * tanhf(cst);
      if (lane == 0){
        astf(bufB + unit, hn);
        astf(anch + (size_t)(t + 1) * DDIM + unit, hn);
      }
    }
    bar_arrive(barctr); tgt += KWG;      // B3 (only wg0 waits; others take oflag chain)

    int oi;
    if (wg == 0){
      bar_wait(barctr, tgt);             // full h2 visible
      {
        float hc2[8]; load8(bufB + (lane << 3), hc2);
        for (int i = wave; i < 16; i += 16){
          float acc = 0.f;
          #pragma unroll
          for (int k = 0; k < 8; ++k) acc += s_opfc[i * DDIM + (lane << 3) + k] * hc2[k];
          acc = wredsum(acc);
          if (lane == 0) s_oplog[i] = tanhf(acc / 5.0f);  // (2.5/2.5)=1.0 scale
        }
      }
      __syncthreads();
      if (wave == 0){
        // 16 random bits: bits[i] = x0 ^ x1 of tf(k2, (0, i))
        uint32_t z0 = 0, z1 = 0;
        if (lane < 16) tf2x32(k2a_s, k2b_s, 0u, (uint32_t)lane, z0, z1);
        uint32_t bits = z0 ^ z1;
        float gmb   = gumbel_bits(bits);
        float logit = (lane < 16) ? s_oplog[lane] : -3.0e38f;
        float cand  = (lane < 16) ? (logit + gmb) : -3.0e38f;
        float v = cand; int bi = lane;
        #pragma unroll
        for (int m = 32; m; m >>= 1){
          float ov = __shfl_xor(v, m, 64); int ob = __shfl_xor(bi, m, 64);
          if (ov > v || (ov == v && ob < bi)){ v = ov; bi = ob; }
        }
        int oi_ = bi;
        float lm = (lane < 16) ? logit : -3.0e38f;
        #pragma unroll
        for (int m = 32; m; m >>= 1) lm = fmaxf(lm, __shfl_xor(lm, m, 64));
        float ex   = (lane < 16) ? expf(logit - lm) : 0.f;
        float ssum = wredsum(ex);
        float olsm = logit - lm - logf(ssum);
        float olp  = -__shfl(olsm, oi_, 64);
        float oent = wredsum((lane < 16) ? (-olsm * expf(olsm)) : 0.f);
        lp_sum  += nlp_s + olp;
        ent_sum += nent_s + oent;
        if (lane == 0){
          s_ibc[1] = oi_;
          out[2 * t]     = (float)ni;
          out[2 * t + 1] = (float)oi_;
          __hip_atomic_store(oflag + t, 0x5A5A0000u | (uint32_t)oi_,
                             __ATOMIC_RELEASE, __HIP_MEMORY_SCOPE_AGENT);
        }
      }
      __syncthreads();
      oi = s_ibc[1];
    } else {
      if (tid == 0){
        uint32_t v;
        while (((v = aldu(oflag + t)) >> 16) != 0x5A5Au) __builtin_amdgcn_s_sleep(1);
        s_ibc[1] = (int)(v & 0xFFFFu);
      }
      __syncthreads();
      __builtin_amdgcn_fence(__ATOMIC_ACQUIRE, "agent");
      oi = s_ibc[1];
    }
    prev_op = oi;
  }

  if (wg == 0 && wave == 0 && lane == 0){
    out[64] = ent_sum;
    out[65] = lp_sum;
  }
}

extern "C" void kernel_launch(void* const* d_in, const int* in_sizes, int n_in,
                              void* d_out, int out_size, void* d_ws, size_t ws_size,
                              hipStream_t stream) {
  (void)in_sizes; (void)n_in; (void)out_size; (void)ws_size;
  const float* emb  = (const float*)d_in[0];
  const float* wih  = (const float*)d_in[1];
  const float* whh  = (const float*)d_in[2];
  const float* bih  = (const float*)d_in[3];
  const float* bhh  = (const float*)d_in[4];
  const float* wa1  = (const float*)d_in[5];
  const float* wa2  = (const float*)d_in[6];
  const float* ifc  = (const float*)d_in[7];
  const float* ofc  = (const float*)d_in[8];
  float* out = (float*)d_out;
  uint32_t* ws = (uint32_t*)d_ws;
  hipLaunchKernelGGL(Controller_60601988547087_kernel,
                     dim3(KWG), dim3(NTH), 0, stream,
                     emb, wih, whh, bih, bhh, wa1, wa2, ifc, ofc, out, ws);
}

// Round 4
// 1186.820 us; speedup vs baseline: 1.6285x; 1.3946x over previous
//
#include <hip/hip_runtime.h>
#include <stdint.h>

// Persistent-kernel LSTM NAS controller rollout.
// RNG: JAX threefry2x32, jax_threefry_partitionable=True (default >=0.4.36):
//   split row i = tf(key,(0,i)); random_bits[i] = fold x0^x1 of tf(key,(0,i)).
// 64 wgs x 512 thr (8 waves/WG, 512 waves; one hidden unit per wave, weights
// register-stationary — __launch_bounds__(512,2) keeps VGPR cap at 256 so the
// ~110-reg weight set does NOT spill; round-3's 1024-thr shape spilled at 64
// VGPR and paid 101 MB of wbl2 writeback).
// Sync: 3 monotone-counter barriers/step. NO sampler broadcast — every WG
// redundantly computes logits + threefry sampling (bit-identical results),
// removing 2 chained sync hops per step.

#define KWG    64
#define NTH    512
#define LSTEPS 32
#define DDIM   512
#define NOPS   16
#define NEGC   (-1.0e9f)
#define MAGICV 0x13579BDFu

// ---------------- threefry2x32 core ----------------
static __device__ __forceinline__ void tf2x32(uint32_t k0, uint32_t k1,
                                              uint32_t c0, uint32_t c1,
                                              uint32_t& o0, uint32_t& o1){
  uint32_t ks2 = k0 ^ k1 ^ 0x1BD11BDAu;
  uint32_t x0 = c0 + k0;
  uint32_t x1 = c1 + k1;
#define TFR(r) { x0 += x1; x1 = (x1 << (r)) | (x1 >> (32 - (r))); x1 ^= x0; }
  TFR(13) TFR(15) TFR(26) TFR(6)
  x0 += k1;  x1 += ks2 + 1u;
  TFR(17) TFR(29) TFR(16) TFR(24)
  x0 += ks2; x1 += k0 + 2u;
  TFR(13) TFR(15) TFR(26) TFR(6)
  x0 += k0;  x1 += k1 + 3u;
  TFR(17) TFR(29) TFR(16) TFR(24)
  x0 += k1;  x1 += ks2 + 4u;
  TFR(13) TFR(15) TFR(26) TFR(6)
  x0 += ks2; x1 += k0 + 5u;
#undef TFR
  o0 = x0; o1 = x1;
}

static __device__ __forceinline__ float gumbel_bits(uint32_t bits){
  float f = __uint_as_float((bits >> 9) | 0x3f800000u) - 1.0f;
  float u = (f == 0.0f) ? 1.1754943508222875e-38f : f;
  return -logf(-logf(u));
}

static __device__ __forceinline__ float sigm(float x){
  return 1.0f / (1.0f + expf(-x));
}

static __device__ __forceinline__ float wredsum(float v){
  #pragma unroll
  for (int m = 32; m; m >>= 1) v += __shfl_xor(v, m, 64);
  return v;
}

static __device__ __forceinline__ void load8(const float* __restrict__ p, float* r){
  const float4* q = (const float4*)p;
  float4 a = q[0], b = q[1];
  r[0]=a.x; r[1]=a.y; r[2]=a.z; r[3]=a.w;
  r[4]=b.x; r[5]=b.y; r[6]=b.z; r[7]=b.w;
}

static __device__ __forceinline__ float dot8(const float* w, const float* x){
  float s = 0.f;
  #pragma unroll
  for (int k = 0; k < 8; ++k) s += w[k]*x[k];
  return s;
}

static __device__ __forceinline__ uint32_t aldu(const uint32_t* p){
  return __hip_atomic_load(p, __ATOMIC_RELAXED, __HIP_MEMORY_SCOPE_AGENT);
}
static __device__ __forceinline__ void astf(float* p, float v){
  __hip_atomic_store(p, v, __ATOMIC_RELAXED, __HIP_MEMORY_SCOPE_AGENT);
}

// arrive: fence data stores to the coherence point, wg-barrier, one thread
// bumps the global monotone arrival counter.
static __device__ __forceinline__ void bar_arrive(uint32_t* ctr){
  __builtin_amdgcn_fence(__ATOMIC_RELEASE, "agent");
  __syncthreads();
  if (threadIdx.x == 0)
    __hip_atomic_fetch_add(ctr, 1u, __ATOMIC_RELAXED, __HIP_MEMORY_SCOPE_AGENT);
}

// wait: ONE thread polls (s_sleep backoff), then all threads acquire-fence.
static __device__ __forceinline__ void bar_wait(const uint32_t* ctr, uint32_t tgt){
  if (threadIdx.x == 0){
    while (aldu(ctr) < tgt) __builtin_amdgcn_s_sleep(1);
  }
  __syncthreads();
  __builtin_amdgcn_fence(__ATOMIC_ACQUIRE, "agent");
}

__global__ void __launch_bounds__(NTH, 2)
Controller_60601988547087_kernel(const float* __restrict__ emb,
                                 const float* __restrict__ wih,
                                 const float* __restrict__ whh,
                                 const float* __restrict__ bih,
                                 const float* __restrict__ bhh,
                                 const float* __restrict__ wa1,
                                 const float* __restrict__ wa2,
                                 const float* __restrict__ idxfc,
                                 const float* __restrict__ opfc,
                                 float* __restrict__ out,
                                 uint32_t* __restrict__ wsu)
{
  const int tid  = threadIdx.x;
  const int wg   = blockIdx.x;
  const int wave = tid >> 6;              // 0..7
  const int lane = tid & 63;
  const int unit = (wg << 3) | wave;      // one hidden unit per wave, 512 total

  // workspace layout (u32 units)
  uint32_t* magicf = wsu;                 // [64] stride 16 (64B lines)
  uint32_t* barctr = wsu + 1536;          // single monotone arrival counter
  float*    wsf    = (float*)(wsu + 4096);
  float*    bufA   = wsf;                 // h after cell1   [512]
  float*    bufB   = wsf + 512;           // h after cell2 / carry h [512]
  float*    hw2g   = wsf + 1024;          // h1 @ w_attn_2^T [512]
  float*    aw1g   = wsf + 1536;          // anchors_w1 [33][512]
  float*    anch   = wsf + 18432;         // anchors    [33][512]

  __shared__ float s_opfc[NOPS * DDIM];   // 32 KB (every WG stages it)
  __shared__ float s_logits[33];
  __shared__ float s_oplog[16];
  __shared__ int   s_ibc[2];

  // ---- stage weights into registers (read from HBM/L2 once) ----
  float wihr[4][8], whhr[4][8], a1r[8], a2r[8], fcr[8], bsum[4];
  #pragma unroll
  for (int g = 0; g < 4; ++g){
    load8(wih + (size_t)((g << 9) + unit) * DDIM + (lane << 3), wihr[g]);
    load8(whh + (size_t)((g << 9) + unit) * DDIM + (lane << 3), whhr[g]);
    bsum[g] = bih[(g << 9) + unit] + bhh[(g << 9) + unit];
  }
  load8(wa1 + (size_t)unit * DDIM + (lane << 3), a1r);
  load8(wa2 + (size_t)unit * DDIM + (lane << 3), a2r);
  load8(idxfc + (lane << 3), fcr);

  for (int i = tid; i < NOPS * DDIM; i += NTH) s_opfc[i] = opfc[i];

  // ---- initial construct_node: h,c = cell(emb[16], 0, 0) ----
  float cst;
  {
    float xc[8];
    load8(emb + (size_t)NOPS * DDIM + (lane << 3), xc);
    float p0 = dot8(wihr[0], xc);
    float p2 = dot8(wihr[2], xc);
    float p3 = dot8(wihr[3], xc);
    p0 = wredsum(p0); p2 = wredsum(p2); p3 = wredsum(p3);
    float gi = sigm(p0 + bsum[0]);
    float go = sigm(p3 + bsum[3]);
    cst = gi * tanhf(p2 + bsum[2]);      // c=0: forget-gate term vanishes exactly
    float h0 = go * tanhf(cst);
    if (lane == 0){
      astf(bufB + unit, h0);             // carry h
      astf(anch + unit, 0.0f);           // anchors[0] = zeros
    }
  }
  // zero the arrival counter before anyone can touch it (0xAA poison!)
  if (wg == 0 && tid == 0)
    __hip_atomic_store(barctr, 0u, __ATOMIC_RELAXED, __HIP_MEMORY_SCOPE_AGENT);
  // init barrier: exact-match magic (poison-safe: 0xAAAAAAAA != MAGICV)
  __builtin_amdgcn_fence(__ATOMIC_RELEASE, "agent");
  __syncthreads();
  if (tid == 0)
    __hip_atomic_store(magicf + (wg << 4), MAGICV, __ATOMIC_RELEASE, __HIP_MEMORY_SCOPE_AGENT);
  if (tid < KWG){
    while (aldu(magicf + (tid << 4)) != MAGICV) __builtin_amdgcn_s_sleep(1);
  }
  __syncthreads();
  __builtin_amdgcn_fence(__ATOMIC_ACQUIRE, "agent");

  uint32_t key0 = 0u, key1v = 42u;       // jax.random.key(42) -> (0, 42)
  float ent_sum = 0.f, lp_sum = 0.f;
  int prev_op = NOPS;                    // inp0 = embedding[16]
  uint32_t tgt = 0;                      // barrier target (monotone counter)

  for (int t = 0; t < LSTEPS; ++t){
    // ================= Stage A: cell1 + anchors_w1[t] =================
    {
      float xc[8], hc[8];
      load8(emb + (size_t)prev_op * DDIM + (lane << 3), xc);
      load8(bufB + (lane << 3), hc);
      float p0 = dot8(wihr[0], xc) + dot8(whhr[0], hc);
      float p1 = dot8(wihr[1], xc) + dot8(whhr[1], hc);
      float p2 = dot8(wihr[2], xc) + dot8(whhr[2], hc);
      float p3 = dot8(wihr[3], xc) + dot8(whhr[3], hc);
      float pa = dot8(a1r, hc);          // aw1[t][unit] from carry h
      p0 = wredsum(p0); p1 = wredsum(p1); p2 = wredsum(p2); p3 = wredsum(p3);
      pa = wredsum(pa);
      float gi = sigm(p0 + bsum[0]);
      float gf = sigm(p1 + bsum[1]);
      float go = sigm(p3 + bsum[3]);
      cst = gf * cst + gi * tanhf(p2 + bsum[2]);
      float hn = go * tanhf(cst);
      if (lane == 0){
        astf(bufA + unit, hn);
        astf(aw1g + (size_t)t * DDIM + unit, pa);
      }
    }
    bar_arrive(barctr); tgt += KWG;      // B1
    bar_wait(barctr, tgt);               // everyone needs full h1

    // ============ Stage B: hw2 slice, then cell2 h-part (overlaps B2) ============
    {
      float h1c[8];
      load8(bufA + (lane << 3), h1c);
      float q = wredsum(dot8(a2r, h1c));
      if (lane == 0) astf(hw2g + unit, q);
    }
    bar_arrive(barctr); tgt += KWG;      // B2

    float ghh0, ghh1, ghh2, ghh3;        // overlapped with barrier propagation
    {
      float h1c[8];
      load8(bufA + (lane << 3), h1c);
      ghh0 = wredsum(dot8(whhr[0], h1c));
      ghh1 = wredsum(dot8(whhr[1], h1c));
      ghh2 = wredsum(dot8(whhr[2], h1c));
      ghh3 = wredsum(dot8(whhr[3], h1c));
    }
    bar_wait(barctr, tgt);               // full hw2 + aw1g rows visible

    // ======== Node sampling — EVERY WG, redundant & bit-identical ========
    int ni;
    float nlp_s = 0.f, nent_s = 0.f;
    uint32_t k2a_s = 0u, k2b_s = 0u;
    {
      {
        float h2c[8]; load8(hw2g + (lane << 3), h2c);
        for (int i = wave; i <= t; i += 8){
          float ac[8]; load8(aw1g + (size_t)i * DDIM + (lane << 3), ac);
          float acc = 0.f;
          #pragma unroll
          for (int k = 0; k < 8; ++k) acc += tanhf(ac[k] + h2c[k]) * fcr[k];
          acc = wredsum(acc);
          if (lane == 0) s_logits[i] = 2.5f * tanhf(acc / 5.0f);
        }
      }
      __syncthreads();
      if (wave == 0){
        // split(key,3), partitionable/foldlike: row i = tf(key, (0, i))
        uint32_t s0 = 0, s1 = 0;
        if (lane < 3) tf2x32(key0, key1v, 0u, (uint32_t)lane, s0, s1);
        uint32_t k1a = __shfl(s0, 0, 64), k1b = __shfl(s1, 0, 64);
        k2a_s = __shfl(s0, 1, 64); k2b_s = __shfl(s1, 1, 64);
        uint32_t nk0 = __shfl(s0, 2, 64), nk1 = __shfl(s1, 2, 64);
        key0 = nk0; key1v = nk1;
        // 33 random bits: bits[i] = x0 ^ x1 of tf(k1, (0, i))
        uint32_t y0 = 0, y1 = 0;
        if (lane < 33) tf2x32(k1a, k1b, 0u, (uint32_t)lane, y0, y1);
        uint32_t bits = y0 ^ y1;
        float gmb   = gumbel_bits(bits);
        float logit = (lane < 33) ? ((lane <= t) ? s_logits[lane] : NEGC) : -3.0e38f;
        float cand  = (lane < 33) ? (logit + gmb) : -3.0e38f;
        float v = cand; int bi = lane;
        #pragma unroll
        for (int m = 32; m; m >>= 1){
          float ov = __shfl_xor(v, m, 64); int ob = __shfl_xor(bi, m, 64);
          if (ov > v || (ov == v && ob < bi)){ v = ov; bi = ob; }
        }
        int ni_ = bi;
        float lm = (lane < 33) ? logit : -3.0e38f;
        #pragma unroll
        for (int m = 32; m; m >>= 1) lm = fmaxf(lm, __shfl_xor(lm, m, 64));
        float ex   = (lane < 33) ? expf(logit - lm) : 0.f;
        float ssum = wredsum(ex);
        float lsm  = logit - lm - logf(ssum);
        nlp_s  = -__shfl(lsm, ni_, 64);
        float entc = (lane <= t) ? (-lsm * expf(lsm)) : 0.f;
        nent_s = wredsum(entc);
        if (lane == 0) s_ibc[0] = ni_;
      }
      __syncthreads();
      ni = s_ibc[0];
    }

    // ================= Stage C: cell2 (op_in = anchors[ni]) =================
    {
      float oc8[8];
      load8(anch + (size_t)ni * DDIM + (lane << 3), oc8);
      float q0 = dot8(wihr[0], oc8);
      float q1 = dot8(wihr[1], oc8);
      float q2 = dot8(wihr[2], oc8);
      float q3 = dot8(wihr[3], oc8);
      q0 = wredsum(q0); q1 = wredsum(q1); q2 = wredsum(q2); q3 = wredsum(q3);
      float gi = sigm(q0 + ghh0 + bsum[0]);
      float gf = sigm(q1 + ghh1 + bsum[1]);
      float go = sigm(q3 + ghh3 + bsum[3]);
      cst = gf * cst + gi * tanhf(q2 + ghh2 + bsum[2]);
      float hn = go * tanhf(cst);
      if (lane == 0){
        astf(bufB + unit, hn);
        astf(anch + (size_t)(t + 1) * DDIM + unit, hn);
      }
    }
    bar_arrive(barctr); tgt += KWG;      // B3
    bar_wait(barctr, tgt);               // full h2 visible

    // ======== Op sampling — EVERY WG, redundant & bit-identical ========
    int oi;
    {
      {
        float hc2[8]; load8(bufB + (lane << 3), hc2);
        for (int i = wave; i < 16; i += 8){
          float acc = 0.f;
          #pragma unroll
          for (int k = 0; k < 8; ++k) acc += s_opfc[i * DDIM + (lane << 3) + k] * hc2[k];
          acc = wredsum(acc);
          if (lane == 0) s_oplog[i] = tanhf(acc / 5.0f);  // (2.5/2.5)=1.0 scale
        }
      }
      __syncthreads();
      if (wave == 0){
        // 16 random bits: bits[i] = x0 ^ x1 of tf(k2, (0, i))
        uint32_t z0 = 0, z1 = 0;
        if (lane < 16) tf2x32(k2a_s, k2b_s, 0u, (uint32_t)lane, z0, z1);
        uint32_t bits = z0 ^ z1;
        float gmb   = gumbel_bits(bits);
        float logit = (lane < 16) ? s_oplog[lane] : -3.0e38f;
        float cand  = (lane < 16) ? (logit + gmb) : -3.0e38f;
        float v = cand; int bi = lane;
        #pragma unroll
        for (int m = 32; m; m >>= 1){
          float ov = __shfl_xor(v, m, 64); int ob = __shfl_xor(bi, m, 64);
          if (ov > v || (ov == v && ob < bi)){ v = ov; bi = ob; }
        }
        int oi_ = bi;
        float lm = (lane < 16) ? logit : -3.0e38f;
        #pragma unroll
        for (int m = 32; m; m >>= 1) lm = fmaxf(lm, __shfl_xor(lm, m, 64));
        float ex   = (lane < 16) ? expf(logit - lm) : 0.f;
        float ssum = wredsum(ex);
        float olsm = logit - lm - logf(ssum);
        float olp  = -__shfl(olsm, oi_, 64);
        float oent = wredsum((lane < 16) ? (-olsm * expf(olsm)) : 0.f);
        lp_sum  += nlp_s + olp;
        ent_sum += nent_s + oent;
        if (lane == 0){
          s_ibc[1] = oi_;
          if (wg == 0){
            out[2 * t]     = (float)ni;
            out[2 * t + 1] = (float)oi_;
          }
        }
      }
      __syncthreads();
      oi = s_ibc[1];
    }
    prev_op = oi;
  }

  if (wg == 0 && wave == 0 && lane == 0){
    out[64] = ent_sum;
    out[65] = lp_sum;
  }
}

extern "C" void kernel_launch(void* const* d_in, const int* in_sizes, int n_in,
                              void* d_out, int out_size, void* d_ws, size_t ws_size,
                              hipStream_t stream) {
  (void)in_sizes; (void)n_in; (void)out_size; (void)ws_size;
  const float* emb  = (const float*)d_in[0];
  const float* wih  = (const float*)d_in[1];
  const float* whh  = (const float*)d_in[2];
  const float* bih  = (const float*)d_in[3];
  const float* bhh  = (const float*)d_in[4];
  const float* wa1  = (const float*)d_in[5];
  const float* wa2  = (const float*)d_in[6];
  const float* ifc  = (const float*)d_in[7];
  const float* ofc  = (const float*)d_in[8];
  float* out = (float*)d_out;
  uint32_t* ws = (uint32_t*)d_ws;
  hipLaunchKernelGGL(Controller_60601988547087_kernel,
                     dim3(KWG), dim3(NTH), 0, stream,
                     emb, wih, whh, bih, bhh, wa1, wa2, ifc, ofc, out, ws);
}

// Round 5
// 564.005 us; speedup vs baseline: 3.4267x; 2.1043x over previous
//
#include <hip/hip_runtime.h>
#include <stdint.h>

// Persistent-kernel LSTM NAS controller rollout — FENCE-FREE tagged dataflow.
// All cross-WG data = 8-byte relaxed AGENT atomics packing (tag<<32)|f32bits.
// Agent atomics are performed at the coherence point (MALL) -> no wbl2/inv
// fences needed (rounds 2&4 both paid ~12us/barrier for L2 flush fences).
// Consumers poll the data's tag directly (poison 0xAAAAAAAA never matches a
// tag). 64 wgs x 512 thr; one hidden unit per wave, weights register-
// stationary (launch_bounds(512,2) -> 256 VGPR cap, no spill).
// Dot mapping d = 64k+lane everywhere -> stride-64 LDS reads (2-way, free).
// RNG: JAX threefry2x32, jax_threefry_partitionable (verified bit-exact).

#define KWG    64
#define NTH    512
#define LSTEPS 32
#define DDIM   512
#define NOPS   16
#define NEGC   (-1.0e9f)

// ---------------- threefry2x32 core ----------------
static __device__ __forceinline__ void tf2x32(uint32_t k0, uint32_t k1,
                                              uint32_t c0, uint32_t c1,
                                              uint32_t& o0, uint32_t& o1){
  uint32_t ks2 = k0 ^ k1 ^ 0x1BD11BDAu;
  uint32_t x0 = c0 + k0;
  uint32_t x1 = c1 + k1;
#define TFR(r) { x0 += x1; x1 = (x1 << (r)) | (x1 >> (32 - (r))); x1 ^= x0; }
  TFR(13) TFR(15) TFR(26) TFR(6)
  x0 += k1;  x1 += ks2 + 1u;
  TFR(17) TFR(29) TFR(16) TFR(24)
  x0 += ks2; x1 += k0 + 2u;
  TFR(13) TFR(15) TFR(26) TFR(6)
  x0 += k0;  x1 += k1 + 3u;
  TFR(17) TFR(29) TFR(16) TFR(24)
  x0 += k1;  x1 += ks2 + 4u;
  TFR(13) TFR(15) TFR(26) TFR(6)
  x0 += ks2; x1 += k0 + 5u;
#undef TFR
  o0 = x0; o1 = x1;
}

static __device__ __forceinline__ float gumbel_bits(uint32_t bits){
  float f = __uint_as_float((bits >> 9) | 0x3f800000u) - 1.0f;
  float u = (f == 0.0f) ? 1.1754943508222875e-38f : f;
  return -logf(-logf(u));
}

static __device__ __forceinline__ float sigm(float x){
  return 1.0f / (1.0f + expf(-x));
}

static __device__ __forceinline__ float wredsum(float v){
  #pragma unroll
  for (int m = 32; m; m >>= 1) v += __shfl_xor(v, m, 64);
  return v;
}

// gather 8 elems at stride 64: d = 64k + lane  (works for global and LDS)
static __device__ __forceinline__ void gl8(const float* __restrict__ p, int lane, float* r){
  #pragma unroll
  for (int k = 0; k < 8; ++k) r[k] = p[(k << 6) + lane];
}

static __device__ __forceinline__ float dot8(const float* w, const float* x){
  float s = 0.f;
  #pragma unroll
  for (int k = 0; k < 8; ++k) s += w[k]*x[k];
  return s;
}

// ---------------- tagged-atomic helpers ----------------
static __device__ __forceinline__ uint64_t tpack(uint32_t tag, float f){
  return ((uint64_t)tag << 32) | (uint64_t)__float_as_uint(f);
}
static __device__ __forceinline__ uint64_t ald64(const uint64_t* p){
  return __hip_atomic_load(p, __ATOMIC_RELAXED, __HIP_MEMORY_SCOPE_AGENT);
}
static __device__ __forceinline__ void ast64(uint64_t* p, uint64_t v){
  __hip_atomic_store(p, v, __ATOMIC_RELAXED, __HIP_MEMORY_SCOPE_AGENT);
}
static __device__ __forceinline__ float poll1(const uint64_t* p, uint32_t tag){
  uint64_t v = ald64(p);
  while ((uint32_t)(v >> 32) != tag){
    __builtin_amdgcn_s_sleep(1);
    v = ald64(p);
  }
  return __uint_as_float((uint32_t)v);
}
// poll 8 elems (d = 64k+lane) of one tagged row; all 8 loads in flight/iter
static __device__ __forceinline__ void poll8s(const uint64_t* base, int lane,
                                              uint32_t tag, float* r){
  uint64_t v[8];
  for (;;){
    #pragma unroll
    for (int k = 0; k < 8; ++k) v[k] = ald64(base + (k << 6) + lane);
    bool ok = true;
    #pragma unroll
    for (int k = 0; k < 8; ++k) ok &= ((uint32_t)(v[k] >> 32) == tag);
    if (ok) break;
    __builtin_amdgcn_s_sleep(1);
  }
  #pragma unroll
  for (int k = 0; k < 8; ++k) r[k] = __uint_as_float((uint32_t)v[k]);
}

__global__ void __launch_bounds__(NTH, 2)
Controller_60601988547087_kernel(const float* __restrict__ emb,
                                 const float* __restrict__ wih,
                                 const float* __restrict__ whh,
                                 const float* __restrict__ bih,
                                 const float* __restrict__ bhh,
                                 const float* __restrict__ wa1,
                                 const float* __restrict__ wa2,
                                 const float* __restrict__ idxfc,
                                 const float* __restrict__ opfc,
                                 float* __restrict__ out,
                                 uint64_t* __restrict__ ws64)
{
  const int tid  = threadIdx.x;
  const int wg   = blockIdx.x;
  const int wave = tid >> 6;              // 0..7
  const int lane = tid & 63;
  const int unit = (wg << 3) | wave;      // one hidden unit per wave, 512 total

  // workspace (u64 tagged cells)
  uint64_t* bufA64 = ws64;                          // h1      [512]
  uint64_t* bufB64 = ws64 + 512;                    // h2      [512]
  uint64_t* hw2g64 = ws64 + 1024;                   // W2.h1   [512]
  uint64_t* aw1g64 = ws64 + 1536;                   // aw1 rows[32][512]
  uint64_t* anch64 = ws64 + 1536 + 32*512;          // anchors [32][512] (row0 unused)

  __shared__ float s_hc[DDIM];    // carry h / h2 staging
  __shared__ float s_h1[DDIM];    // h after cell1
  __shared__ float s_hw2[DDIM];   // h1 @ w_attn_2^T
  __shared__ float s_arow[DDIM];  // anchors[ni]
  __shared__ float s_logits[33];
  __shared__ float s_oplog[16];
  __shared__ int   s_ibc[2];

  // ---- weights register-stationary, gathered at d = 64k+lane ----
  float wihr[4][8], whhr[4][8], a1r[8], a2r[8], fcr[8], bsum[4];
  #pragma unroll
  for (int g = 0; g < 4; ++g){
    gl8(wih + (size_t)((g << 9) + unit) * DDIM, lane, wihr[g]);
    gl8(whh + (size_t)((g << 9) + unit) * DDIM, lane, whhr[g]);
    bsum[g] = bih[(g << 9) + unit] + bhh[(g << 9) + unit];
  }
  gl8(wa1 + (size_t)unit * DDIM, lane, a1r);
  gl8(wa2 + (size_t)unit * DDIM, lane, a2r);
  gl8(idxfc, lane, fcr);

  // per-wave register cache of aw1 rows (row i owned by wave i&7, slot i>>3)
  float row0[8], row1[8], row2[8], row3[8];

  // ---- initial construct_node: h,c = cell(emb[16], 0, 0), publish tag 1 ----
  float cst;
  {
    float xc[8];
    gl8(emb + (size_t)NOPS * DDIM, lane, xc);
    float p0 = wredsum(dot8(wihr[0], xc));
    float p2 = wredsum(dot8(wihr[2], xc));
    float p3 = wredsum(dot8(wihr[3], xc));
    float gi = sigm(p0 + bsum[0]);
    float go = sigm(p3 + bsum[3]);
    cst = gi * tanhf(p2 + bsum[2]);      // c=0: forget-gate term vanishes exactly
    float h0 = go * tanhf(cst);
    if (lane == 0) ast64(bufB64 + unit, tpack(1u, h0));
  }
  // stage carry h (tag 1)
  s_hc[tid] = poll1(bufB64 + tid, 1u);
  __syncthreads();

  uint32_t key0 = 0u, key1v = 42u;       // jax.random.key(42) -> (0, 42)
  float ent_sum = 0.f, lp_sum = 0.f;
  int prev_op = NOPS;                    // inp0 = embedding[16]

  for (int t = 0; t < LSTEPS; ++t){
    const uint32_t tagA = 4u*(uint32_t)t + 2u;
    const uint32_t tagB = 4u*(uint32_t)t + 3u;
    const uint32_t tagC = 4u*(uint32_t)t + 4u;

    // ================= Stage A: cell1 + aw1 row t =================
    {
      float xc[8], hcv[8];
      gl8(emb + (size_t)prev_op * DDIM, lane, xc);
      gl8(s_hc, lane, hcv);
      float p0 = wredsum(dot8(wihr[0], xc) + dot8(whhr[0], hcv));
      float p1 = wredsum(dot8(wihr[1], xc) + dot8(whhr[1], hcv));
      float p2 = wredsum(dot8(wihr[2], xc) + dot8(whhr[2], hcv));
      float p3 = wredsum(dot8(wihr[3], xc) + dot8(whhr[3], hcv));
      float pa = wredsum(dot8(a1r, hcv));
      float gi = sigm(p0 + bsum[0]);
      float gf = sigm(p1 + bsum[1]);
      float go = sigm(p3 + bsum[3]);
      cst = gf * cst + gi * tanhf(p2 + bsum[2]);
      float hn = go * tanhf(cst);
      if (lane == 0){
        ast64(bufA64 + unit, tpack(tagA, hn));
        ast64(aw1g64 + (size_t)t * DDIM + unit, tpack(tagA, pa));
      }
    }
    // hop A: stage h1; owner wave caches aw1 row t in registers
    s_h1[tid] = poll1(bufA64 + tid, tagA);
    if (wave == (t & 7)){
      const uint64_t* rb = aw1g64 + (size_t)t * DDIM;
      int slot = t >> 3;
      if      (slot == 0) poll8s(rb, lane, tagA, row0);
      else if (slot == 1) poll8s(rb, lane, tagA, row1);
      else if (slot == 2) poll8s(rb, lane, tagA, row2);
      else                poll8s(rb, lane, tagA, row3);
    }
    __syncthreads();

    // ============ Stage B: hw2 slice publish, then cell2 h-part ============
    float ghh0, ghh1, ghh2, ghh3;
    {
      float h1c[8];
      gl8(s_h1, lane, h1c);
      float q = wredsum(dot8(a2r, h1c));
      if (lane == 0) ast64(hw2g64 + unit, tpack(tagB, q));
      ghh0 = wredsum(dot8(whhr[0], h1c));   // overlaps others' hw2 publishes
      ghh1 = wredsum(dot8(whhr[1], h1c));
      ghh2 = wredsum(dot8(whhr[2], h1c));
      ghh3 = wredsum(dot8(whhr[3], h1c));
    }
    // hop B: stage hw2
    s_hw2[tid] = poll1(hw2g64 + tid, tagB);
    __syncthreads();

    // ======== Node logits + sampling — EVERY WG, bit-identical ========
    int ni;
    float nlp_s = 0.f, nent_s = 0.f;
    uint32_t k2a_s = 0u, k2b_s = 0u;
    {
      float h2c[8];
      gl8(s_hw2, lane, h2c);
#define ROWDOT(RR, I)                                                          \
      { int i_ = (I);                                                          \
        if (i_ <= t){                                                          \
          float acc = 0.f;                                                     \
          _Pragma("unroll")                                                    \
          for (int k = 0; k < 8; ++k) acc += tanhf(RR[k] + h2c[k]) * fcr[k];   \
          acc = wredsum(acc);                                                  \
          if (lane == 0) s_logits[i_] = 2.5f * tanhf(acc / 5.0f);              \
        } }
      ROWDOT(row0, wave)
      ROWDOT(row1, wave + 8)
      ROWDOT(row2, wave + 16)
      ROWDOT(row3, wave + 24)
#undef ROWDOT
      __syncthreads();
      if (wave == 0){
        // split(key,3), partitionable/foldlike: row i = tf(key, (0, i))
        uint32_t s0 = 0, s1 = 0;
        if (lane < 3) tf2x32(key0, key1v, 0u, (uint32_t)lane, s0, s1);
        uint32_t k1a = __shfl(s0, 0, 64), k1b = __shfl(s1, 0, 64);
        k2a_s = __shfl(s0, 1, 64); k2b_s = __shfl(s1, 1, 64);
        uint32_t nk0 = __shfl(s0, 2, 64), nk1 = __shfl(s1, 2, 64);
        key0 = nk0; key1v = nk1;
        // 33 random bits: bits[i] = x0 ^ x1 of tf(k1, (0, i))
        uint32_t y0 = 0, y1 = 0;
        if (lane < 33) tf2x32(k1a, k1b, 0u, (uint32_t)lane, y0, y1);
        uint32_t bits = y0 ^ y1;
        float gmb   = gumbel_bits(bits);
        float logit = (lane < 33) ? ((lane <= t) ? s_logits[lane] : NEGC) : -3.0e38f;
        float cand  = (lane < 33) ? (logit + gmb) : -3.0e38f;
        float v = cand; int bi = lane;
        #pragma unroll
        for (int m = 32; m; m >>= 1){
          float ov = __shfl_xor(v, m, 64); int ob = __shfl_xor(bi, m, 64);
          if (ov > v || (ov == v && ob < bi)){ v = ov; bi = ob; }
        }
        int ni_ = bi;
        float lm = (lane < 33) ? logit : -3.0e38f;
        #pragma unroll
        for (int m = 32; m; m >>= 1) lm = fmaxf(lm, __shfl_xor(lm, m, 64));
        float ex   = (lane < 33) ? expf(logit - lm) : 0.f;
        float ssum = wredsum(ex);
        float lsm  = logit - lm - logf(ssum);
        nlp_s  = -__shfl(lsm, ni_, 64);
        float entc = (lane <= t) ? (-lsm * expf(lsm)) : 0.f;
        nent_s = wredsum(entc);
        if (lane == 0) s_ibc[0] = ni_;
      }
      __syncthreads();
      ni = s_ibc[0];
    }

    // ================= Stage C: cell2 (op_in = anchors[ni]) =================
    // anchors row r (r>=1) was published at step r-1 with tag 4r; row 0 = zeros
    if (ni > 0) s_arow[tid] = poll1(anch64 + (size_t)ni * DDIM + tid, 4u * (uint32_t)ni);
    else        s_arow[tid] = 0.f;
    __syncthreads();
    {
      float oc8[8];
      gl8(s_arow, lane, oc8);
      float q0 = wredsum(dot8(wihr[0], oc8));
      float q1 = wredsum(dot8(wihr[1], oc8));
      float q2 = wredsum(dot8(wihr[2], oc8));
      float q3 = wredsum(dot8(wihr[3], oc8));
      float gi = sigm(q0 + ghh0 + bsum[0]);
      float gf = sigm(q1 + ghh1 + bsum[1]);
      float go = sigm(q3 + ghh3 + bsum[3]);
      cst = gf * cst + gi * tanhf(q2 + ghh2 + bsum[2]);
      float hn = go * tanhf(cst);
      if (lane == 0){
        ast64(bufB64 + unit, tpack(tagC, hn));
        if (t < LSTEPS - 1)
          ast64(anch64 + (size_t)(t + 1) * DDIM + unit, tpack(tagC, hn));
      }
    }
    // hop C: stage h2 (serves op-logits AND next step's carry h)
    s_hc[tid] = poll1(bufB64 + tid, tagC);
    __syncthreads();

    // ======== Op logits + sampling — EVERY WG, bit-identical ========
    int oi;
    {
      float hc2[8];
      gl8(s_hc, lane, hc2);
      #pragma unroll
      for (int jj = 0; jj < 2; ++jj){
        int i = wave + (jj << 3);
        const float* wrow = opfc + (size_t)i * DDIM;
        float acc = 0.f;
        #pragma unroll
        for (int k = 0; k < 8; ++k) acc += wrow[(k << 6) + lane] * hc2[k];
        acc = wredsum(acc);
        if (lane == 0) s_oplog[i] = tanhf(acc / 5.0f);  // (2.5/2.5)=1 scale
      }
      __syncthreads();
      if (wave == 0){
        // 16 random bits: bits[i] = x0 ^ x1 of tf(k2, (0, i))
        uint32_t z0 = 0, z1 = 0;
        if (lane < 16) tf2x32(k2a_s, k2b_s, 0u, (uint32_t)lane, z0, z1);
        uint32_t bits = z0 ^ z1;
        float gmb   = gumbel_bits(bits);
        float logit = (lane < 16) ? s_oplog[lane] : -3.0e38f;
        float cand  = (lane < 16) ? (logit + gmb) : -3.0e38f;
        float v = cand; int bi = lane;
        #pragma unroll
        for (int m = 32; m; m >>= 1){
          float ov = __shfl_xor(v, m, 64); int ob = __shfl_xor(bi, m, 64);
          if (ov > v || (ov == v && ob < bi)){ v = ov; bi = ob; }
        }
        int oi_ = bi;
        float lm = (lane < 16) ? logit : -3.0e38f;
        #pragma unroll
        for (int m = 32; m; m >>= 1) lm = fmaxf(lm, __shfl_xor(lm, m, 64));
        float ex   = (lane < 16) ? expf(logit - lm) : 0.f;
        float ssum = wredsum(ex);
        float olsm = logit - lm - logf(ssum);
        float olp  = -__shfl(olsm, oi_, 64);
        float oent = wredsum((lane < 16) ? (-olsm * expf(olsm)) : 0.f);
        lp_sum  += nlp_s + olp;
        ent_sum += nent_s + oent;
        if (lane == 0){
          s_ibc[1] = oi_;
          if (wg == 0){
            out[2 * t]     = (float)ni;
            out[2 * t + 1] = (float)oi_;
          }
        }
      }
      __syncthreads();
      oi = s_ibc[1];
    }
    prev_op = oi;
  }

  if (wg == 0 && wave == 0 && lane == 0){
    out[64] = ent_sum;
    out[65] = lp_sum;
  }
}

extern "C" void kernel_launch(void* const* d_in, const int* in_sizes, int n_in,
                              void* d_out, int out_size, void* d_ws, size_t ws_size,
                              hipStream_t stream) {
  (void)in_sizes; (void)n_in; (void)out_size; (void)ws_size;
  const float* emb  = (const float*)d_in[0];
  const float* wih  = (const float*)d_in[1];
  const float* whh  = (const float*)d_in[2];
  const float* bih  = (const float*)d_in[3];
  const float* bhh  = (const float*)d_in[4];
  const float* wa1  = (const float*)d_in[5];
  const float* wa2  = (const float*)d_in[6];
  const float* ifc  = (const float*)d_in[7];
  const float* ofc  = (const float*)d_in[8];
  float* out = (float*)d_out;
  uint64_t* ws = (uint64_t*)d_ws;
  hipLaunchKernelGGL(Controller_60601988547087_kernel,
                     dim3(KWG), dim3(NTH), 0, stream,
                     emb, wih, whh, bih, bhh, wa1, wa2, ifc, ofc, out, ws);
}